// Round 13
// baseline (646.367 us; speedup 1.0000x reference)
//
#include <hip/hip_runtime.h>
#include <hip/hip_bf16.h>
#include <math.h>

#define N_USERS 50000
#define N_ITEMS 30000
#define N_ENT   100000
#define NE      500000      // KG edges E (== 32 * 15625, exact)
#define NEI     1000000     // interaction edges EI
#define D       64
#define GAMMA   0.2f
#define LDP     65          // padded LDS stride: conflict-free staging

#define UBK ((N_USERS + 255) / 256)   // 196 user buckets
#define HBK ((N_ENT + 255) / 256)     // 391 head buckets
#define PCHUNK 4096                   // edges per pass-1 block

typedef __hip_bfloat16 bf16;

__device__ __forceinline__ float wave_sum(float v) {
    #pragma unroll
    for (int off = 32; off > 0; off >>= 1) v += __shfl_xor(v, off, 64);
    return v;
}

__device__ __forceinline__ float g16_sum(float v) {
    #pragma unroll
    for (int off = 1; off < 16; off <<= 1) v += __shfl_xor(v, off, 64);
    return v;
}

__device__ __forceinline__ float bits2f(unsigned short u) {
    return __uint_as_float(((unsigned)u) << 16);
}

__device__ __forceinline__ unsigned short f2bf_bits(float f) {
    bf16 b = __float2bfloat16(f);
    return *(unsigned short*)&b;
}

// fast sigmoid: v_exp_f32 + rcp pipe (absmax gated by bf16 hops)
__device__ __forceinline__ float sigmoidf(float x) {
    return __fdividef(1.0f, 1.0f + __expf(-x));
}

__device__ __forceinline__ float n2n(float y) {
    if (isnan(y)) return 0.0f;
    if (isinf(y)) return y > 0.0f ? 1e4f : 1e-4f;
    return y;
}

// ================= CSR build: bucketed 2-pass multisplit =================
__global__ __launch_bounds__(256) void k_histb(const int* __restrict__ ie,
        const int* __restrict__ eidx, int* __restrict__ bcntU,
        int* __restrict__ bcntH, int UCH) {
    __shared__ int lc[HBK + 1];
    int t = threadIdx.x;
    int b = blockIdx.x;
    for (int i = t; i < HBK + 1; i += 256) lc[i] = 0;
    __syncthreads();
    if (b < UCH) {
        int base = b * PCHUNK;
        #pragma unroll
        for (int i = 0; i < PCHUNK / 256; i++) {
            int e = base + i * 256 + t;
            if (e < NEI) atomicAdd(&lc[ie[e] >> 8], 1);
        }
        __syncthreads();
        for (int i = t; i < UBK; i += 256) if (lc[i]) atomicAdd(&bcntU[i], lc[i]);
    } else {
        int base = (b - UCH) * PCHUNK;
        #pragma unroll
        for (int i = 0; i < PCHUNK / 256; i++) {
            int e = base + i * 256 + t;
            if (e < NE) atomicAdd(&lc[eidx[e] >> 8], 1);
        }
        __syncthreads();
        for (int i = t; i < HBK; i += 256) if (lc[i]) atomicAdd(&bcntH[i], lc[i]);
    }
}

__global__ void k_scanb(const int* __restrict__ bcntU, int* __restrict__ bOffU,
                        int* __restrict__ bcurU, const int* __restrict__ bcntH,
                        int* __restrict__ bOffH, int* __restrict__ bcurH,
                        int* __restrict__ offU, int* __restrict__ offH) {
    __shared__ int sh[512];
    int t = threadIdx.x;
    const int* c; int* o; int* cu; int n; int tot;
    if (blockIdx.x == 0) { c = bcntU; o = bOffU; cu = bcurU; n = UBK; tot = NEI; }
    else                 { c = bcntH; o = bOffH; cu = bcurH; n = HBK; tot = NE; }
    int v = (t < n) ? c[t] : 0;
    sh[t] = v;
    __syncthreads();
    for (int d = 1; d < 512; d <<= 1) {
        int x = (t >= d) ? sh[t - d] : 0;
        __syncthreads();
        sh[t] += x;
        __syncthreads();
    }
    if (t < n) { int ex = sh[t] - v; o[t] = ex; cu[t] = ex; }
    if (t == 0) {
        o[n] = tot;
        if (blockIdx.x == 0) offU[N_USERS] = NEI;
        else                 offH[N_ENT] = NE;
    }
}

__global__ __launch_bounds__(256) void k_part1(const int* __restrict__ ie,
        const float* __restrict__ w, const int* __restrict__ eidx,
        const int* __restrict__ etype, int* __restrict__ bcurU,
        int* __restrict__ bcurH, int2* __restrict__ stIW,
        int* __restrict__ stTR, int UCH) {
    __shared__ int lcnt[HBK + 1];
    __shared__ int lbase[HBK + 1];
    int t = threadIdx.x;
    int b = blockIdx.x;
    for (int i = t; i < HBK + 1; i += 256) lcnt[i] = 0;
    __syncthreads();
    if (b < UCH) {
        int base = b * PCHUNK;
        int bkt[PCHUNK / 256], rnk[PCHUNK / 256];
        #pragma unroll
        for (int i = 0; i < PCHUNK / 256; i++) {
            int e = base + i * 256 + t;
            bkt[i] = -1;
            rnk[i] = 0;
            if (e < NEI) {
                int k = ie[e] >> 8;
                bkt[i] = k;
                rnk[i] = atomicAdd(&lcnt[k], 1);
            }
        }
        __syncthreads();
        for (int i = t; i < UBK; i += 256)
            if (lcnt[i] > 0) lbase[i] = atomicAdd(&bcurU[i], lcnt[i]);
        __syncthreads();
        #pragma unroll
        for (int i = 0; i < PCHUNK / 256; i++) {
            int e = base + i * 256 + t;
            if (bkt[i] >= 0) {
                int pos = lbase[bkt[i]] + rnk[i];
                int ul = ie[e] & 255;
                stIW[pos] = make_int2(ie[NEI + e] | (ul << 24), __float_as_int(w[e]));
            }
        }
    } else {
        int base = (b - UCH) * PCHUNK;
        int bkt[PCHUNK / 256], rnk[PCHUNK / 256];
        #pragma unroll
        for (int i = 0; i < PCHUNK / 256; i++) {
            int e = base + i * 256 + t;
            bkt[i] = -1;
            rnk[i] = 0;
            if (e < NE) {
                int k = eidx[e] >> 8;
                bkt[i] = k;
                rnk[i] = atomicAdd(&lcnt[k], 1);
            }
        }
        __syncthreads();
        for (int i = t; i < HBK; i += 256)
            if (lcnt[i] > 0) lbase[i] = atomicAdd(&bcurH[i], lcnt[i]);
        __syncthreads();
        #pragma unroll
        for (int i = 0; i < PCHUNK / 256; i++) {
            int e = base + i * 256 + t;
            if (bkt[i] >= 0) {
                int pos = lbase[bkt[i]] + rnk[i];
                int hl = eidx[e] & 255;
                stTR[pos] = eidx[NE + e] | ((etype[e] - 1) << 20) | (hl << 24);
            }
        }
    }
}

// ================= lane-owns-row tiled GEMM helpers (padded stride LDP) =================
__device__ __forceinline__ void stage_rows2(const float* __restrict__ s0,
                                            const float* __restrict__ s1,
                                            float* At, int row0, int n, int t) {
    #pragma unroll
    for (int half = 0; half < 2; half++) {
        const float* src = half ? s1 : s0;
        int kofs = half ? 32 : 0;
        #pragma unroll
        for (int fi = t, it = 0; it < 2; fi += 256, it++) {
            int row = fi >> 3;
            int k4 = (fi & 7) << 2;
            float4 v = make_float4(0.f, 0.f, 0.f, 0.f);
            if (row0 + row < n) v = *(const float4*)&src[(size_t)(row0 + row) * 32 + k4];
            At[(kofs + k4 + 0) * LDP + row] = v.x;
            At[(kofs + k4 + 1) * LDP + row] = v.y;
            At[(kofs + k4 + 2) * LDP + row] = v.z;
            At[(kofs + k4 + 3) * LDP + row] = v.w;
        }
    }
}

__device__ __forceinline__ void stage_rows1(const float* __restrict__ src,
                                            float* At, int row0, int n, int t) {
    #pragma unroll
    for (int fi = t, it = 0; it < 4; fi += 256, it++) {
        int row = fi >> 4;
        int k4 = (fi & 15) << 2;
        float4 v = make_float4(0.f, 0.f, 0.f, 0.f);
        if (row0 + row < n) v = *(const float4*)&src[(size_t)(row0 + row) * 64 + k4];
        At[(k4 + 0) * LDP + row] = v.x;
        At[(k4 + 1) * LDP + row] = v.y;
        At[(k4 + 2) * LDP + row] = v.z;
        At[(k4 + 3) * LDP + row] = v.w;
    }
}

// ================= k_part2e: part2 scatter blocks interleaved with ent-GEMM =================
// PB = UBK + HBK part2 blocks; EB ent-GEMM blocks.
//   b < 2*PB : even -> part2[b/2], odd -> ent[b/2]
//   b >= 2*PB: ent[PB + b - 2*PB]          (PB <= EB)
__global__ __launch_bounds__(256) void k_part2e(const int* __restrict__ bOffU,
        const int2* __restrict__ stIW, int* __restrict__ offU,
        int2* __restrict__ csr_itw, const int* __restrict__ bOffH,
        const int* __restrict__ stTR, int* __restrict__ offH,
        int2* __restrict__ csr_th,
        const float* __restrict__ er, const float* __restrict__ ei,
        const float* __restrict__ fpW1, const float* __restrict__ rtW1,
        float* __restrict__ EH, float* __restrict__ ET, float* __restrict__ PHI,
        int UBKc, int PB, int EB) {
    __shared__ float At[64 * LDP];
    int* lcnt = (int*)At;
    int* lcur = (int*)At + 256;
    int b = blockIdx.x;
    int t = threadIdx.x;
    int role, idx;          // role 0 = part2, 1 = ent GEMM
    if (b < 2 * PB) { role = b & 1; idx = b >> 1; }
    else            { role = 1;     idx = PB + (b - 2 * PB); }
    if (role == 1) {
        // ---- entity GEMM: EH/ET (acc[32]) + PHI (acp[16]) from one staging ----
        int row0 = idx << 6;
        stage_rows2(er, ei, At, row0, N_ENT, t);
        __syncthreads();
        int lane = t & 63;
        int wv = __builtin_amdgcn_readfirstlane(t >> 6);
        int row = row0 + lane;
        const float* Wb1 = fpW1 + ((wv >> 1) ? (128 * 64) : 0) + (wv & 1) * 32;
        const float* Wb2 = rtW1 + wv * 16;
        float acc[32];
        float acp[16];
        #pragma unroll
        for (int c = 0; c < 32; c++) acc[c] = 0.f;
        #pragma unroll
        for (int c = 0; c < 16; c++) acp[c] = 0.f;
        for (int k = 0; k < 64; k++) {
            float a = At[k * LDP + lane];
            const float* wr1 = Wb1 + k * 64;
            const float* wr2 = Wb2 + k * 64;
            #pragma unroll
            for (int c4 = 0; c4 < 8; c4++) {
                float4 w4 = *(const float4*)&wr1[c4 * 4];
                acc[c4 * 4 + 0] += a * w4.x;
                acc[c4 * 4 + 1] += a * w4.y;
                acc[c4 * 4 + 2] += a * w4.z;
                acc[c4 * 4 + 3] += a * w4.w;
            }
            #pragma unroll
            for (int c4 = 0; c4 < 4; c4++) {
                float4 w4 = *(const float4*)&wr2[c4 * 4];
                acp[c4 * 4 + 0] += a * w4.x;
                acp[c4 * 4 + 1] += a * w4.y;
                acp[c4 * 4 + 2] += a * w4.z;
                acp[c4 * 4 + 3] += a * w4.w;
            }
        }
        if (row < N_ENT) {
            float* dst = ((wv >> 1) ? ET : EH) + (size_t)row * 64 + (wv & 1) * 32;
            #pragma unroll
            for (int c4 = 0; c4 < 8; c4++)
                *(float4*)&dst[c4 * 4] = make_float4(acc[c4*4], acc[c4*4+1], acc[c4*4+2], acc[c4*4+3]);
            float* dsp = PHI + (size_t)row * 64 + wv * 16;
            #pragma unroll
            for (int c4 = 0; c4 < 4; c4++)
                *(float4*)&dsp[c4 * 4] = make_float4(acp[c4*4], acp[c4*4+1], acp[c4*4+2], acp[c4*4+3]);
        }
        return;
    }
    // ---- part2 scatter ----
    lcnt[t] = 0;
    __syncthreads();
    if (idx < UBKc) {
        int bb = idx;
        int s = bOffU[bb], e = bOffU[bb + 1];
        for (int j = s + t; j < e; j += 256)
            atomicAdd(&lcnt[((unsigned)stIW[j].x) >> 24], 1);
        __syncthreads();
        int v = lcnt[t];
        lcur[t] = v;
        __syncthreads();
        for (int d = 1; d < 256; d <<= 1) {
            int x = (t >= d) ? lcur[t - d] : 0;
            __syncthreads();
            lcur[t] += x;
            __syncthreads();
        }
        int base = s + lcur[t] - v;
        int u = (bb << 8) + t;
        if (u < N_USERS) offU[u] = base;
        __syncthreads();
        lcur[t] = base;
        __syncthreads();
        for (int j = s + t; j < e; j += 256) {
            int2 r = stIW[j];
            int pos = atomicAdd(&lcur[((unsigned)r.x) >> 24], 1);
            csr_itw[pos] = make_int2(r.x & 0x00FFFFFF, r.y);
        }
    } else {
        int bb = idx - UBKc;
        int s = bOffH[bb], e = bOffH[bb + 1];
        for (int j = s + t; j < e; j += 256)
            atomicAdd(&lcnt[((unsigned)stTR[j]) >> 24], 1);
        __syncthreads();
        int v = lcnt[t];
        lcur[t] = v;
        __syncthreads();
        for (int d = 1; d < 256; d <<= 1) {
            int x = (t >= d) ? lcur[t - d] : 0;
            __syncthreads();
            lcur[t] += x;
            __syncthreads();
        }
        int base = s + lcur[t] - v;
        int h = (bb << 8) + t;
        if (h < N_ENT) offH[h] = base;
        __syncthreads();
        lcur[t] = base;
        __syncthreads();
        for (int j = s + t; j < e; j += 256) {
            int r = stTR[j];
            int pos = atomicAdd(&lcur[((unsigned)r) >> 24], 1);
            csr_th[pos] = make_int2(r & 0x00FFFFFF,
                                    (bb << 8) + (int)(((unsigned)r) >> 24));
        }
    }
}

// ================= k_proj: item/user projections + rel tables =================
__global__ __launch_bounds__(256) void k_proj(const float* __restrict__ I,
        const float* __restrict__ Wk, const float* __restrict__ Wv,
        const float* __restrict__ UE, const float* __restrict__ Wq,
        bf16* __restrict__ IkB, float* __restrict__ Iv, float* __restrict__ Uq,
        const float* __restrict__ fpW1, const float* __restrict__ rr,
        const float* __restrict__ ri, const float* __restrict__ rtW1,
        float* __restrict__ RR1, float* __restrict__ PSI, int IB, int UB) {
    __shared__ float At[64 * LDP];
    int t = threadIdx.x;
    int b = blockIdx.x;
    int lane = t & 63;
    int wv = __builtin_amdgcn_readfirstlane(t >> 6);
    if (b < IB) {
        int row0 = b << 6;
        stage_rows1(I, At, row0, N_ITEMS, t);
        __syncthreads();
        const float* Wb = ((wv >> 1) ? Wv : Wk) + (wv & 1) * 32;
        float acc[32];
        #pragma unroll
        for (int c = 0; c < 32; c++) acc[c] = 0.f;
        for (int k = 0; k < 64; k++) {
            float a = At[k * LDP + lane];
            const float* wr = Wb + k * 64;
            #pragma unroll
            for (int c4 = 0; c4 < 8; c4++) {
                float4 w4 = *(const float4*)&wr[c4 * 4];
                acc[c4 * 4 + 0] += a * w4.x;
                acc[c4 * 4 + 1] += a * w4.y;
                acc[c4 * 4 + 2] += a * w4.z;
                acc[c4 * 4 + 3] += a * w4.w;
            }
        }
        int row = row0 + lane;
        if (row < N_ITEMS) {
            if (wv >> 1) {
                float* dst = Iv + (size_t)row * 64 + (wv & 1) * 32;
                #pragma unroll
                for (int c4 = 0; c4 < 8; c4++)
                    *(float4*)&dst[c4 * 4] = make_float4(acc[c4*4], acc[c4*4+1], acc[c4*4+2], acc[c4*4+3]);
            } else {
                bf16* dst = IkB + (size_t)row * 64 + (wv & 1) * 32;
                #pragma unroll
                for (int c4 = 0; c4 < 8; c4++) {
                    ushort4 s;
                    s.x = f2bf_bits(acc[c4 * 4 + 0]);
                    s.y = f2bf_bits(acc[c4 * 4 + 1]);
                    s.z = f2bf_bits(acc[c4 * 4 + 2]);
                    s.w = f2bf_bits(acc[c4 * 4 + 3]);
                    *(ushort4*)&dst[c4 * 4] = s;
                }
            }
        }
    } else if (b < IB + UB) {
        int row0 = (b - IB) << 6;
        stage_rows1(UE, At, row0, N_USERS, t);
        __syncthreads();
        const float* Wb = Wq + wv * 16;
        float acc[16];
        #pragma unroll
        for (int c = 0; c < 16; c++) acc[c] = 0.f;
        for (int k = 0; k < 64; k++) {
            float a = At[k * LDP + lane];
            const float* wr = Wb + k * 64;
            #pragma unroll
            for (int c4 = 0; c4 < 4; c4++) {
                float4 w4 = *(const float4*)&wr[c4 * 4];
                acc[c4 * 4 + 0] += a * w4.x;
                acc[c4 * 4 + 1] += a * w4.y;
                acc[c4 * 4 + 2] += a * w4.z;
                acc[c4 * 4 + 3] += a * w4.w;
            }
        }
        int row = row0 + lane;
        if (row < N_USERS) {
            float* dst = Uq + (size_t)row * 64 + wv * 16;
            #pragma unroll
            for (int c4 = 0; c4 < 4; c4++)
                *(float4*)&dst[c4 * 4] = make_float4(acc[c4*4], acc[c4*4+1], acc[c4*4+2], acc[c4*4+3]);
        }
    } else {
        if (t < 64) {
            int lane2 = t;
            for (int r = 0; r < 10; r++) {
                float a = 0.f, bb = 0.f;
                for (int k = 0; k < 32; k++) {
                    float sr = rr[r * 32 + k], si = ri[r * 32 + k];
                    a  += sr * fpW1[(64 + k) * D + lane2] + si * fpW1[(96 + k) * D + lane2];
                    bb += sr * rtW1[k * D + lane2] + si * rtW1[(32 + k) * D + lane2];
                }
                RR1[r * D + lane2] = a;
                PSI[r * D + lane2] = bb;
            }
        }
    }
}

// ================= Stage A: fused scores+softmax+scatter =================
__global__ __launch_bounds__(256) void k_userAB(const int* __restrict__ offU,
                        const int2* __restrict__ itw,
                        const float* __restrict__ Uq, const bf16* __restrict__ IkB,
                        float* __restrict__ exA, float* __restrict__ c, int n) {
    int u = (blockIdx.x * blockDim.x + threadIdx.x) >> 6;
    int lane = threadIdx.x & 63;
    if (u >= n) return;
    int s = offU[u], e = offU[u + 1];
    if (s == e) return;
    int l = lane & 15, g = lane >> 4;
    float4 qv = *(const float4*)&Uq[(size_t)u * D + l * 4];
    const char* kbase = (const char*)IkB;
    unsigned dby = (unsigned)(l << 3);
    float den = 0.f;
    for (int j0 = s; j0 < e; j0 += 8) {
        int jA = j0 + g, jB = jA + 4;
        bool vA = jA < e, vB = jB < e;
        int2 iA = itw[vA ? jA : s];
        int2 iB = itw[vB ? jB : s];
        ushort4 kA = *(const ushort4*)(kbase + (((unsigned)iA.x) << 7) + dby);
        ushort4 kB = *(const ushort4*)(kbase + (((unsigned)iB.x) << 7) + dby);
        float dA = qv.x * bits2f(kA.x) + qv.y * bits2f(kA.y) +
                   qv.z * bits2f(kA.z) + qv.w * bits2f(kA.w);
        float dB = qv.x * bits2f(kB.x) + qv.y * bits2f(kB.y) +
                   qv.z * bits2f(kB.z) + qv.w * bits2f(kB.w);
        #pragma unroll
        for (int off = 1; off < 16; off <<= 1) {
            dA += __shfl_xor(dA, off, 64);
            dB += __shfl_xor(dB, off, 64);
        }
        float eAv = vA ? __expf(dA * 0.125f * __int_as_float(iA.y)) : 0.f;
        float eBv = vB ? __expf(dB * 0.125f * __int_as_float(iB.y)) : 0.f;
        den += eAv + eBv;
        if (vA && l == 0) exA[jA] = eAv;
        if (vB && l == 0) exA[jB] = eBv;
    }
    den += __shfl_xor(den, 16, 64);
    den += __shfl_xor(den, 32, 64);
    float inv = __fdividef(1.0f, den * (float)(e - s));   // 1/(den*deg)
    asm volatile("s_waitcnt vmcnt(0)" ::: "memory");
    for (int j = s + lane; j < e; j += 64)
        atomicAdd(&c[itw[j].x], exA[j] * inv);
}

__global__ void k_pdense(const float* __restrict__ c, const float* __restrict__ Iv,
                         float* __restrict__ p, int n) {
    int lane = threadIdx.x & 63;
    int gw = blockIdx.x * 4 + (threadIdx.x >> 6);
    int nw = gridDim.x * 4;
    float acc = 0.f;
    for (int i = gw; i < n; i += nw) acc += c[i] * Iv[(size_t)i * D + lane];
    __shared__ float red[256];
    red[threadIdx.x] = acc;
    __syncthreads();
    if (threadIdx.x < 64) {
        float s = red[threadIdx.x] + red[threadIdx.x + 64] + red[threadIdx.x + 128] + red[threadIdx.x + 192];
        atomicAdd(&p[threadIdx.x], s);
    }
}

// v2 = rtW2 @ p ; cb = <rt_b2, p>
__global__ void k_v2(const float* __restrict__ rtW2, const float* __restrict__ rt_b2,
                     const float* __restrict__ p, float* __restrict__ v2,
                     float* __restrict__ cb) {
    int j = threadIdx.x;
    if (j < 64) {
        float acc = 0.f;
        #pragma unroll
        for (int k = 0; k < D; k++) acc += rtW2[j * D + k] * p[k];
        v2[j] = acc;
        float cc = rt_b2[j] * p[j];
        cc = wave_sum(cc);
        if (j == 0) cb[0] = cc;
    }
}

// ================= omega pass 1: EDGE-PARALLEL gates + omega =================
__global__ __launch_bounds__(256) void k_omegaE(const int2* __restrict__ csr_th,
                          const float* __restrict__ EH, const float* __restrict__ ET,
                          const float* __restrict__ PHI, const float* __restrict__ PSI,
                          const float* __restrict__ RR1, const float* __restrict__ fp_b1,
                          const float* __restrict__ fpW2, const float* __restrict__ fp_b2,
                          const float* __restrict__ rt_b1, const float* __restrict__ v2,
                          const float* __restrict__ cb, float* __restrict__ omg,
                          const float* __restrict__ src_emb, bf16* __restrict__ eA,
                          int NB) {
    int b = blockIdx.x;
    if (b >= NB) {
        int base = (b - NB) * 1024 + threadIdx.x * 4;
        float4 v = *(const float4*)&src_emb[base];
        ushort4 s;
        s.x = f2bf_bits(v.x); s.y = f2bf_bits(v.y);
        s.z = f2bf_bits(v.z); s.w = f2bf_bits(v.w);
        *(ushort4*)&eA[base] = s;
        return;
    }
    int grp = threadIdx.x >> 4;
    int l = threadIdx.x & 15;
    int d0 = l * 4;
    int jA = b * 32 + grp;
    int jB = jA + 16;
    float4 b1 = *(const float4*)&fp_b1[d0];
    float4 rb = *(const float4*)&rt_b1[d0];
    float4 vv = *(const float4*)&v2[d0];
    float cc = cb[0];
    float f0[4], f1[4], f2[4];
    #pragma unroll
    for (int c4 = 0; c4 < 4; c4++) {
        f0[c4] = fpW2[(d0 + c4) * 3 + 0];
        f1[c4] = fpW2[(d0 + c4) * 3 + 1];
        f2[c4] = fpW2[(d0 + c4) * 3 + 2];
    }
    float b20 = fp_b2[0], b21 = fp_b2[1], b22 = fp_b2[2];
    int2 thA = csr_th[jA];
    int2 thB = csr_th[jB];
    int tA = thA.x & 0xFFFFF, rA = thA.x >> 20, hA = thA.y;
    int tB = thB.x & 0xFFFFF, rB = thB.x >> 20, hB = thB.y;
    float4 ehA = *(const float4*)&EH[(size_t)hA * D + d0];
    float4 ehB = *(const float4*)&EH[(size_t)hB * D + d0];
    float4 phA = *(const float4*)&PHI[(size_t)hA * D + d0];
    float4 phB = *(const float4*)&PHI[(size_t)hB * D + d0];
    float4 etA = *(const float4*)&ET[(size_t)tA * D + d0];
    float4 etB = *(const float4*)&ET[(size_t)tB * D + d0];
    float4 ptA = *(const float4*)&PHI[(size_t)tA * D + d0];
    float4 ptB = *(const float4*)&PHI[(size_t)tB * D + d0];
    float4 rrA = *(const float4*)&RR1[rA * D + d0];
    float4 rrB = *(const float4*)&RR1[rB * D + d0];
    float4 psA = *(const float4*)&PSI[rA * D + d0];
    float4 psB = *(const float4*)&PSI[rB * D + d0];
    ehA.x += b1.x; ehA.y += b1.y; ehA.z += b1.z; ehA.w += b1.w;
    ehB.x += b1.x; ehB.y += b1.y; ehB.z += b1.z; ehB.w += b1.w;
    float zA0 = sigmoidf(ehA.x + rrA.x + etA.x);
    float zA1 = sigmoidf(ehA.y + rrA.y + etA.y);
    float zA2 = sigmoidf(ehA.z + rrA.z + etA.z);
    float zA3 = sigmoidf(ehA.w + rrA.w + etA.w);
    float zB0 = sigmoidf(ehB.x + rrB.x + etB.x);
    float zB1 = sigmoidf(ehB.y + rrB.y + etB.y);
    float zB2 = sigmoidf(ehB.z + rrB.z + etB.z);
    float zB3 = sigmoidf(ehB.w + rrB.w + etB.w);
    float v[6];
    v[0] = zA0 * f0[0] + zA1 * f0[1] + zA2 * f0[2] + zA3 * f0[3];
    v[1] = zA0 * f1[0] + zA1 * f1[1] + zA2 * f1[2] + zA3 * f1[3];
    v[2] = zA0 * f2[0] + zA1 * f2[1] + zA2 * f2[2] + zA3 * f2[3];
    v[3] = zB0 * f0[0] + zB1 * f0[1] + zB2 * f0[2] + zB3 * f0[3];
    v[4] = zB0 * f1[0] + zB1 * f1[1] + zB2 * f1[2] + zB3 * f1[3];
    v[5] = zB0 * f2[0] + zB1 * f2[1] + zB2 * f2[2] + zB3 * f2[3];
    #pragma unroll
    for (int off = 1; off < 16; off <<= 1) {
        #pragma unroll
        for (int q = 0; q < 6; q++) v[q] += __shfl_xor(v[q], off, 64);
    }
    float a0 = v[0] + b20, a1 = v[1] + b21, a2 = v[2] + b22;
    float mx = fmaxf(a0, fmaxf(a1, a2));
    float e0 = __expf(a0 - mx), e1 = __expf(a1 - mx), e2 = __expf(a2 - mx);
    float isum = __fdividef(1.0f, e0 + e1 + e2);
    float WA0 = e0 * isum, WA1 = e1 * isum, WA2 = e2 * isum;
    a0 = v[3] + b20; a1 = v[4] + b21; a2 = v[5] + b22;
    mx = fmaxf(a0, fmaxf(a1, a2));
    e0 = __expf(a0 - mx); e1 = __expf(a1 - mx); e2 = __expf(a2 - mx);
    isum = __fdividef(1.0f, e0 + e1 + e2);
    float WB0 = e0 * isum, WB1 = e1 * isum, WB2 = e2 * isum;
    float svA = sigmoidf(WA0 * phA.x + WA1 * psA.x + WA2 * ptA.x + rb.x) * vv.x
              + sigmoidf(WA0 * phA.y + WA1 * psA.y + WA2 * ptA.y + rb.y) * vv.y
              + sigmoidf(WA0 * phA.z + WA1 * psA.z + WA2 * ptA.z + rb.z) * vv.z
              + sigmoidf(WA0 * phA.w + WA1 * psA.w + WA2 * ptA.w + rb.w) * vv.w;
    float svB = sigmoidf(WB0 * phB.x + WB1 * psB.x + WB2 * ptB.x + rb.x) * vv.x
              + sigmoidf(WB0 * phB.y + WB1 * psB.y + WB2 * ptB.y + rb.y) * vv.y
              + sigmoidf(WB0 * phB.z + WB1 * psB.z + WB2 * ptB.z + rb.z) * vv.z
              + sigmoidf(WB0 * phB.w + WB1 * psB.w + WB2 * ptB.w + rb.w) * vv.w;
    #pragma unroll
    for (int off = 1; off < 16; off <<= 1) {
        svA += __shfl_xor(svA, off, 64);
        svB += __shfl_xor(svB, off, 64);
    }
    if (l == 0) {
        omg[jA] = (svA + cc) * 0.125f;
        omg[jB] = (svB + cc) * 0.125f;
    }
}

// ================= omega pass 2: per-head segO + alpha + eta =================
__global__ __launch_bounds__(256) void k_omegaS(const int* __restrict__ offH,
                          const int2* __restrict__ csr_th,
                          const float* __restrict__ omg,
                          int2* __restrict__ pa, int2* __restrict__ pe, int n) {
    int h = (blockIdx.x * 256 + threadIdx.x) >> 4;
    int l = threadIdx.x & 15;
    if (h >= n) return;
    int s = offH[h], e = offH[h + 1];
    if (s == e) return;
    float so = 0.f;
    for (int j = s + l; j < e; j += 16) so += omg[j];
    so = g16_sum(so);
    float invO = __fdividef(1.0f, so + 1e-8f);
    float se = 0.f;
    for (int j = s + l; j < e; j += 16) {
        float a = omg[j] * invO;
        pa[j] = make_int2(csr_th[j].x, __float_as_int(a));
        se += (a > GAMMA) ? a : 0.0f;
    }
    se = g16_sum(se);
    float invE = __fdividef(1.0f, se + 1e-8f);
    for (int j = s + l; j < e; j += 16) {
        float a = omg[j] * invO;
        pe[j] = make_int2(csr_th[j].x, __float_as_int(((a > GAMMA) ? a : 0.0f) * invE));
    }
}

// ================= fused hop: 16-lane group per node =================
// entity side: 2-edge chains (deg~5); user side: 4-edge chains (deg~20)
__global__ __launch_bounds__(256) void k_hop(const int* __restrict__ offH,
                      const int2* __restrict__ rt,
                      const float* __restrict__ rel,
                      const int* __restrict__ offU, const int2* __restrict__ itw,
                      const bf16* __restrict__ ecur, bf16* __restrict__ enxt,
                      const float* __restrict__ initE, const float* __restrict__ initU,
                      float* __restrict__ outE, float* __restrict__ outU,
                      int init, int EB2) {
    int b = blockIdx.x;
    int l = threadIdx.x & 15;
    int d0 = l * 4;
    const char* ebase = (const char*)ecur;
    unsigned dby = (unsigned)(d0 << 1);
    if (b < EB2) {
        int gw = (b * 256 + threadIdx.x) >> 4;
        if (gw >= N_ENT) return;
        int s = offH[gw], e = offH[gw + 1];
        float a0 = 0.f, a1 = 0.f, a2 = 0.f, a3 = 0.f;
        for (int j0 = s; j0 < e; j0 += 2) {
            int jB = j0 + 1;
            bool vB = jB < e;
            int2 pA = rt[j0];
            int2 pB = rt[vB ? jB : j0];
            float rhA = __int_as_float(pA.y);
            float rhB = vB ? __int_as_float(pB.y) : 0.f;
            unsigned tA = (unsigned)pA.x & 0xFFFFFu; int rA = pA.x >> 20;
            unsigned tB = (unsigned)pB.x & 0xFFFFFu; int rB = pB.x >> 20;
            ushort4 evA = *(const ushort4*)(ebase + (tA << 7) + dby);
            ushort4 evB = *(const ushort4*)(ebase + (tB << 7) + dby);
            float4 rlA = *(const float4*)&rel[rA * D + d0];
            float4 rlB = *(const float4*)&rel[rB * D + d0];
            a0 += rhA * bits2f(evA.x) * rlA.x;
            a1 += rhA * bits2f(evA.y) * rlA.y;
            a2 += rhA * bits2f(evA.z) * rlA.z;
            a3 += rhA * bits2f(evA.w) * rlA.w;
            a0 += rhB * bits2f(evB.x) * rlB.x;
            a1 += rhB * bits2f(evB.y) * rlB.y;
            a2 += rhB * bits2f(evB.z) * rlB.z;
            a3 += rhB * bits2f(evB.w) * rlB.w;
        }
        float invd = __fdividef(1.0f, fmaxf((float)(e - s), 1.0f));
        a0 *= invd; a1 *= invd; a2 *= invd; a3 *= invd;
        float ss = a0 * a0 + a1 * a1 + a2 * a2 + a3 * a3;
        ss = g16_sum(ss);
        float nrm = fmaxf(sqrtf(ss), 1e-8f);
        float innrm = __fdividef(1.0f, nrm);
        float y0 = n2n(a0 * innrm), y1 = n2n(a1 * innrm), y2 = n2n(a2 * innrm), y3 = n2n(a3 * innrm);
        ushort4 st;
        st.x = f2bf_bits(y0); st.y = f2bf_bits(y1); st.z = f2bf_bits(y2); st.w = f2bf_bits(y3);
        *(ushort4*)&enxt[(size_t)gw * D + d0] = st;
        size_t o = (size_t)gw * D + d0;
        float4 prev;
        if (init) prev = *(const float4*)&initE[o];
        else      prev = *(const float4*)&outE[o];
        *(float4*)&outE[o] = make_float4(prev.x + y0, prev.y + y1, prev.z + y2, prev.w + y3);
    } else {
        int gw = ((b - EB2) * 256 + threadIdx.x) >> 4;
        if (gw >= N_USERS) return;
        int s = offU[gw], e = offU[gw + 1];
        float a0 = 0.f, a1 = 0.f, a2 = 0.f, a3 = 0.f;
        for (int j0 = s; j0 < e; j0 += 4) {
            int j1 = j0 + 1, j2 = j0 + 2, j3 = j0 + 3;
            bool v1 = j1 < e, v2c = j2 < e, v3 = j3 < e;
            int2 i0 = itw[j0];
            int2 i1 = itw[v1 ? j1 : j0];
            int2 i2 = itw[v2c ? j2 : j0];
            int2 i3 = itw[v3 ? j3 : j0];
            float w0 = __int_as_float(i0.y);
            float w1 = v1 ? __int_as_float(i1.y) : 0.f;
            float w2 = v2c ? __int_as_float(i2.y) : 0.f;
            float w3 = v3 ? __int_as_float(i3.y) : 0.f;
            ushort4 e0 = *(const ushort4*)(ebase + (((unsigned)i0.x) << 7) + dby);
            ushort4 e1 = *(const ushort4*)(ebase + (((unsigned)i1.x) << 7) + dby);
            ushort4 e2 = *(const ushort4*)(ebase + (((unsigned)i2.x) << 7) + dby);
            ushort4 e3 = *(const ushort4*)(ebase + (((unsigned)i3.x) << 7) + dby);
            a0 += w0 * bits2f(e0.x) + w1 * bits2f(e1.x) + w2 * bits2f(e2.x) + w3 * bits2f(e3.x);
            a1 += w0 * bits2f(e0.y) + w1 * bits2f(e1.y) + w2 * bits2f(e2.y) + w3 * bits2f(e3.y);
            a2 += w0 * bits2f(e0.z) + w1 * bits2f(e1.z) + w2 * bits2f(e2.z) + w3 * bits2f(e3.z);
            a3 += w0 * bits2f(e0.w) + w1 * bits2f(e1.w) + w2 * bits2f(e2.w) + w3 * bits2f(e3.w);
        }
        float ss = a0 * a0 + a1 * a1 + a2 * a2 + a3 * a3;
        ss = g16_sum(ss);
        float nrm = fmaxf(sqrtf(ss), 1e-8f);
        float innrm = __fdividef(1.0f, nrm);
        float y0 = n2n(a0 * innrm), y1 = n2n(a1 * innrm), y2 = n2n(a2 * innrm), y3 = n2n(a3 * innrm);
        size_t o = (size_t)gw * D + d0;
        float4 prev;
        if (init) prev = *(const float4*)&initU[o];
        else      prev = *(const float4*)&outU[o];
        *(float4*)&outU[o] = make_float4(prev.x + y0, prev.y + y1, prev.z + y2, prev.w + y3);
    }
}

extern "C" void kernel_launch(void* const* d_in, const int* in_sizes, int n_in,
                              void* d_out, int out_size, void* d_ws, size_t ws_size,
                              hipStream_t stream) {
    const float* user_embed = (const float*)d_in[0];
    const float* item_embed = (const float*)d_in[1];
    const float* Wq = (const float*)d_in[2];
    const float* Wk = (const float*)d_in[3];
    const float* Wv = (const float*)d_in[4];
    const float* ent_real = (const float*)d_in[5];
    const float* ent_imag = (const float*)d_in[6];
    const float* rel_real = (const float*)d_in[7];
    const float* rel_imag = (const float*)d_in[8];
    const float* fp_W1 = (const float*)d_in[9];
    const float* fp_b1 = (const float*)d_in[10];
    const float* fp_W2 = (const float*)d_in[11];
    const float* fp_b2 = (const float*)d_in[12];
    const float* rt_W1 = (const float*)d_in[13];
    const float* rt_b1 = (const float*)d_in[14];
    const float* rt_W2 = (const float*)d_in[15];
    const float* rt_b2 = (const float*)d_in[16];
    const float* relation_emb = (const float*)d_in[17];
    const float* user_emb = (const float*)d_in[18];
    const float* entity_emb = (const float*)d_in[19];
    const float* inter_edge_w = (const float*)d_in[20];
    const int* edge_index = (const int*)d_in[21];
    const int* edge_type = (const int*)d_in[22];
    const int* inter_edge = (const int*)d_in[23];
    float* out = (float*)d_out;

    float* W = (float*)d_ws;
    size_t off = 0;
    auto alloc = [&](size_t n) { float* r = W + off; off += n; return r; };
    // persistent floats
    float* omg    = alloc(NE);
    float* exA    = alloc(NEI);
    float* c      = alloc(N_ITEMS);   // c and p adjacent -> single memset
    float* p      = alloc(64);
    float* v2     = alloc(64);
    float* cb     = alloc(64);
    float* RR1    = alloc(10 * D);
    float* PSI    = alloc(10 * D);
    // persistent ints
    off = (off + 3) & ~(size_t)3;
    int* IW = (int*)(W + off);
    size_t ioff = 0;
    auto ialloc = [&](size_t n) { int* r = IW + ioff; ioff += n; return r; };
    int2* csr_itw = (int2*)ialloc(2 * (size_t)NEI);   // packed (item, wbits)
    int2* pa      = (int2*)ialloc(2 * (size_t)NE);    // packed (tr, alpha)
    int2* pe      = (int2*)ialloc(2 * (size_t)NE);    // packed (tr, eta)
    int2* csr_th  = (int2*)ialloc(2 * (size_t)NE);    // packed (tr, head)
    int* offU   = ialloc(N_USERS + 1);
    int* offH   = ialloc(N_ENT + 1);
    int* bcntU  = ialloc(UBK);                // bcntU/bcntH adjacent -> single memset
    int* bcntH  = ialloc(HBK);
    int* bOffU  = ialloc(UBK + 1);
    int* bOffH  = ialloc(HBK + 1);
    int* bcurU  = ialloc(UBK);
    int* bcurH  = ialloc(HBK);
    off += ioff;
    off = (off + 3) & ~(size_t)3;
    // union region
    float* U = W + off;
    const size_t NED = (size_t)N_ENT * D;        // 6.4M floats
    // layout: [staging 2.5M | tables 3*NED | phase-A 6.08M]
    //   staging dead after part2e's scatter; tables live until omegaE done;
    //   phase-A (IkB/Iv/Uq) live until pdense.
    int2* stIW = (int2*)U;                       // NEI int2 = 2M words
    int*  stTR = (int*)U + 2 * (size_t)NEI;      // +0.5M words -> staging = 2.5M
    float* TB  = U + 2500000;                    // tables base
    float* EH  = TB;
    float* ET  = TB + NED;
    float* PHI = TB + 2 * NED;
    float* XR  = TB + 3 * NED;                   // phase-A base
    bf16*  IkB = (bf16*)XR;
    float* Iv  = XR + (size_t)N_ITEMS * 32;
    float* Uq  = Iv + (size_t)N_ITEMS * D;
    // eA over dead staging region (3.2M words needed > 2.5M staging... use XR side)
    // eA (3.2M words) overlaps IkB/Iv/Uq (6.08M words, dead before omegaE)
    bf16* eA = (bf16*)XR;
    // eB over dead EH region during hops
    bf16* eB = (bf16*)TB;

    const int UCH = (NEI + PCHUNK - 1) / PCHUNK;   // 245
    const int HCH = (NE + PCHUNK - 1) / PCHUNK;    // 123
    const int IB = (N_ITEMS + 63) / 64;            // 469
    const int UB = (N_USERS + 63) / 64;            // 782
    const int EB = (N_ENT + 63) / 64;              // 1563
    const int PB = UBK + HBK;                      // 587  (<= EB)
    const int OEB = NE / 32;                       // 15625 edge blocks (exact)
    const int CB = (N_ENT * D) / 1024;             // cvt blocks (exact)
    const int SB = (N_ENT + 15) / 16;
    const int HE2 = (N_ENT + 15) / 16;
    const int HU2 = (N_USERS + 15) / 16;

    // ---- CSR build ----
    hipMemsetAsync(bcntU, 0, (UBK + HBK) * 4, stream);
    hipMemsetAsync(c, 0, (N_ITEMS + 64) * 4, stream);
    k_histb<<<UCH + HCH, 256, 0, stream>>>(inter_edge, edge_index, bcntU, bcntH, UCH);
    k_scanb<<<2, 512, 0, stream>>>(bcntU, bOffU, bcurU, bcntH, bOffH, bcurH, offU, offH);
    k_part1<<<UCH + HCH, 256, 0, stream>>>(inter_edge, inter_edge_w, edge_index,
                                           edge_type, bcurU, bcurH, stIW, stTR, UCH);
    // part2 scatter + ent GEMM co-scheduled (complementary resource profiles)
    k_part2e<<<PB + EB, 256, 0, stream>>>(bOffU, stIW, offU, csr_itw,
                                          bOffH, stTR, offH, csr_th,
                                          ent_real, ent_imag, fp_W1, rt_W1,
                                          EH, ET, PHI, UBK, PB, EB);

    // ---- Phase A ----
    k_proj<<<IB + UB + 1, 256, 0, stream>>>(item_embed, Wk, Wv, user_embed, Wq,
                                            IkB, Iv, Uq,
                                            fp_W1, rel_real, rel_imag, rt_W1,
                                            RR1, PSI, IB, UB);
    k_userAB<<<(N_USERS + 3) / 4, 256, 0, stream>>>(offU, csr_itw, Uq, IkB, exA, c, N_USERS);
    k_pdense<<<64, 256, 0, stream>>>(c, Iv, p, N_ITEMS);
    k_v2<<<1, 64, 0, stream>>>(rt_W2, rt_b2, p, v2, cb);

    // ---- omega ----
    k_omegaE<<<OEB + CB, 256, 0, stream>>>(csr_th, EH, ET, PHI, PSI, RR1,
                                           fp_b1, fp_W2, fp_b2, rt_b1, v2, cb,
                                           omg, entity_emb, eA, OEB);
    k_omegaS<<<SB, 256, 0, stream>>>(offH, csr_th, omg, pa, pe, N_ENT);

    // ---- hops ----
    bf16* ecur = eA;
    bf16* enxt = eB;
    for (int hop = 1; hop <= 3; hop++) {
        const int2* rt = (hop < 3) ? pa : pe;
        int init = (hop == 1) ? 1 : 0;
        k_hop<<<HE2 + HU2, 256, 0, stream>>>(offH, rt, relation_emb,
                                             offU, csr_itw, ecur, enxt,
                                             entity_emb, user_emb,
                                             out, out + (size_t)N_ENT * D, init, HE2);
        bf16* tmp = ecur; ecur = enxt; enxt = tmp;
    }
}

// Round 14
// 629.557 us; speedup vs baseline: 1.0267x; 1.0267x over previous
//
#include <hip/hip_runtime.h>
#include <hip/hip_bf16.h>
#include <math.h>

#define N_USERS 50000
#define N_ITEMS 30000
#define N_ENT   100000
#define NE      500000      // KG edges E (== 32 * 15625, exact)
#define NEI     1000000     // interaction edges EI
#define D       64
#define GAMMA   0.2f
#define LDP     65          // padded LDS stride: conflict-free staging

#define UBK ((N_USERS + 255) / 256)   // 196 user buckets
#define HBK ((N_ENT + 255) / 256)     // 391 head buckets
#define PCHUNK 4096                   // edges per pass-1 block

typedef __hip_bfloat16 bf16;

__device__ __forceinline__ float wave_sum(float v) {
    #pragma unroll
    for (int off = 32; off > 0; off >>= 1) v += __shfl_xor(v, off, 64);
    return v;
}

__device__ __forceinline__ float g16_sum(float v) {
    #pragma unroll
    for (int off = 1; off < 16; off <<= 1) v += __shfl_xor(v, off, 64);
    return v;
}

__device__ __forceinline__ float bits2f(unsigned short u) {
    return __uint_as_float(((unsigned)u) << 16);
}

__device__ __forceinline__ unsigned short f2bf_bits(float f) {
    bf16 b = __float2bfloat16(f);
    return *(unsigned short*)&b;
}

// fast sigmoid: v_exp_f32 + rcp pipe (absmax gated by bf16 hops)
__device__ __forceinline__ float sigmoidf(float x) {
    return __fdividef(1.0f, 1.0f + __expf(-x));
}

__device__ __forceinline__ float n2n(float y) {
    if (isnan(y)) return 0.0f;
    if (isinf(y)) return y > 0.0f ? 1e4f : 1e-4f;
    return y;
}

// ================= CSR build: bucketed 2-pass multisplit =================
__global__ __launch_bounds__(256) void k_histb(const int* __restrict__ ie,
        const int* __restrict__ eidx, int* __restrict__ bcntU,
        int* __restrict__ bcntH, int UCH) {
    __shared__ int lc[HBK + 1];
    int t = threadIdx.x;
    int b = blockIdx.x;
    for (int i = t; i < HBK + 1; i += 256) lc[i] = 0;
    __syncthreads();
    if (b < UCH) {
        int base = b * PCHUNK;
        #pragma unroll
        for (int i = 0; i < PCHUNK / 256; i++) {
            int e = base + i * 256 + t;
            if (e < NEI) atomicAdd(&lc[ie[e] >> 8], 1);
        }
        __syncthreads();
        for (int i = t; i < UBK; i += 256) if (lc[i]) atomicAdd(&bcntU[i], lc[i]);
    } else {
        int base = (b - UCH) * PCHUNK;
        #pragma unroll
        for (int i = 0; i < PCHUNK / 256; i++) {
            int e = base + i * 256 + t;
            if (e < NE) atomicAdd(&lc[eidx[e] >> 8], 1);
        }
        __syncthreads();
        for (int i = t; i < HBK; i += 256) if (lc[i]) atomicAdd(&bcntH[i], lc[i]);
    }
}

__global__ void k_scanb(const int* __restrict__ bcntU, int* __restrict__ bOffU,
                        int* __restrict__ bcurU, const int* __restrict__ bcntH,
                        int* __restrict__ bOffH, int* __restrict__ bcurH,
                        int* __restrict__ offU, int* __restrict__ offH) {
    __shared__ int sh[512];
    int t = threadIdx.x;
    const int* c; int* o; int* cu; int n; int tot;
    if (blockIdx.x == 0) { c = bcntU; o = bOffU; cu = bcurU; n = UBK; tot = NEI; }
    else                 { c = bcntH; o = bOffH; cu = bcurH; n = HBK; tot = NE; }
    int v = (t < n) ? c[t] : 0;
    sh[t] = v;
    __syncthreads();
    for (int d = 1; d < 512; d <<= 1) {
        int x = (t >= d) ? sh[t - d] : 0;
        __syncthreads();
        sh[t] += x;
        __syncthreads();
    }
    if (t < n) { int ex = sh[t] - v; o[t] = ex; cu[t] = ex; }
    if (t == 0) {
        o[n] = tot;
        if (blockIdx.x == 0) offU[N_USERS] = NEI;
        else                 offH[N_ENT] = NE;
    }
}

__global__ __launch_bounds__(256) void k_part1(const int* __restrict__ ie,
        const float* __restrict__ w, const int* __restrict__ eidx,
        const int* __restrict__ etype, int* __restrict__ bcurU,
        int* __restrict__ bcurH, int2* __restrict__ stIW,
        int* __restrict__ stTR, int UCH) {
    __shared__ int lcnt[HBK + 1];
    __shared__ int lbase[HBK + 1];
    int t = threadIdx.x;
    int b = blockIdx.x;
    for (int i = t; i < HBK + 1; i += 256) lcnt[i] = 0;
    __syncthreads();
    if (b < UCH) {
        int base = b * PCHUNK;
        int bkt[PCHUNK / 256], rnk[PCHUNK / 256];
        #pragma unroll
        for (int i = 0; i < PCHUNK / 256; i++) {
            int e = base + i * 256 + t;
            bkt[i] = -1;
            rnk[i] = 0;
            if (e < NEI) {
                int k = ie[e] >> 8;
                bkt[i] = k;
                rnk[i] = atomicAdd(&lcnt[k], 1);
            }
        }
        __syncthreads();
        for (int i = t; i < UBK; i += 256)
            if (lcnt[i] > 0) lbase[i] = atomicAdd(&bcurU[i], lcnt[i]);
        __syncthreads();
        #pragma unroll
        for (int i = 0; i < PCHUNK / 256; i++) {
            int e = base + i * 256 + t;
            if (bkt[i] >= 0) {
                int pos = lbase[bkt[i]] + rnk[i];
                int ul = ie[e] & 255;
                stIW[pos] = make_int2(ie[NEI + e] | (ul << 24), __float_as_int(w[e]));
            }
        }
    } else {
        int base = (b - UCH) * PCHUNK;
        int bkt[PCHUNK / 256], rnk[PCHUNK / 256];
        #pragma unroll
        for (int i = 0; i < PCHUNK / 256; i++) {
            int e = base + i * 256 + t;
            bkt[i] = -1;
            rnk[i] = 0;
            if (e < NE) {
                int k = eidx[e] >> 8;
                bkt[i] = k;
                rnk[i] = atomicAdd(&lcnt[k], 1);
            }
        }
        __syncthreads();
        for (int i = t; i < HBK; i += 256)
            if (lcnt[i] > 0) lbase[i] = atomicAdd(&bcurH[i], lcnt[i]);
        __syncthreads();
        #pragma unroll
        for (int i = 0; i < PCHUNK / 256; i++) {
            int e = base + i * 256 + t;
            if (bkt[i] >= 0) {
                int pos = lbase[bkt[i]] + rnk[i];
                int hl = eidx[e] & 255;
                stTR[pos] = eidx[NE + e] | ((etype[e] - 1) << 20) | (hl << 24);
            }
        }
    }
}

__global__ __launch_bounds__(256) void k_part2(const int* __restrict__ bOffU,
        const int2* __restrict__ stIW, int* __restrict__ offU,
        int2* __restrict__ csr_itw, const int* __restrict__ bOffH,
        const int* __restrict__ stTR, int* __restrict__ offH,
        int2* __restrict__ csr_th, int UBKc) {
    __shared__ int lcnt[256];
    __shared__ int lcur[256];
    int t = threadIdx.x;
    int b = blockIdx.x;
    lcnt[t] = 0;
    __syncthreads();
    if (b < UBKc) {
        int s = bOffU[b], e = bOffU[b + 1];
        for (int j = s + t; j < e; j += 256)
            atomicAdd(&lcnt[((unsigned)stIW[j].x) >> 24], 1);
        __syncthreads();
        int v = lcnt[t];
        lcur[t] = v;
        __syncthreads();
        for (int d = 1; d < 256; d <<= 1) {
            int x = (t >= d) ? lcur[t - d] : 0;
            __syncthreads();
            lcur[t] += x;
            __syncthreads();
        }
        int base = s + lcur[t] - v;
        int u = (b << 8) + t;
        if (u < N_USERS) offU[u] = base;
        __syncthreads();
        lcur[t] = base;
        __syncthreads();
        for (int j = s + t; j < e; j += 256) {
            int2 r = stIW[j];
            int pos = atomicAdd(&lcur[((unsigned)r.x) >> 24], 1);
            csr_itw[pos] = make_int2(r.x & 0x00FFFFFF, r.y);
        }
    } else {
        int bb = b - UBKc;
        int s = bOffH[bb], e = bOffH[bb + 1];
        for (int j = s + t; j < e; j += 256)
            atomicAdd(&lcnt[((unsigned)stTR[j]) >> 24], 1);
        __syncthreads();
        int v = lcnt[t];
        lcur[t] = v;
        __syncthreads();
        for (int d = 1; d < 256; d <<= 1) {
            int x = (t >= d) ? lcur[t - d] : 0;
            __syncthreads();
            lcur[t] += x;
            __syncthreads();
        }
        int base = s + lcur[t] - v;
        int h = (bb << 8) + t;
        if (h < N_ENT) offH[h] = base;
        __syncthreads();
        lcur[t] = base;
        __syncthreads();
        for (int j = s + t; j < e; j += 256) {
            int r = stTR[j];
            int pos = atomicAdd(&lcur[((unsigned)r) >> 24], 1);
            // (tr, head) packed as one int2 -> single 8B load downstream
            csr_th[pos] = make_int2(r & 0x00FFFFFF,
                                    (bb << 8) + (int)(((unsigned)r) >> 24));
        }
    }
}

// ================= lane-owns-row tiled GEMM helpers (padded stride LDP) =================
__device__ __forceinline__ void stage_rows2(const float* __restrict__ s0,
                                            const float* __restrict__ s1,
                                            float* At, int row0, int n, int t) {
    #pragma unroll
    for (int half = 0; half < 2; half++) {
        const float* src = half ? s1 : s0;
        int kofs = half ? 32 : 0;
        #pragma unroll
        for (int fi = t, it = 0; it < 2; fi += 256, it++) {
            int row = fi >> 3;
            int k4 = (fi & 7) << 2;
            float4 v = make_float4(0.f, 0.f, 0.f, 0.f);
            if (row0 + row < n) v = *(const float4*)&src[(size_t)(row0 + row) * 32 + k4];
            At[(kofs + k4 + 0) * LDP + row] = v.x;
            At[(kofs + k4 + 1) * LDP + row] = v.y;
            At[(kofs + k4 + 2) * LDP + row] = v.z;
            At[(kofs + k4 + 3) * LDP + row] = v.w;
        }
    }
}

__device__ __forceinline__ void stage_rows1(const float* __restrict__ src,
                                            float* At, int row0, int n, int t) {
    #pragma unroll
    for (int fi = t, it = 0; it < 4; fi += 256, it++) {
        int row = fi >> 4;
        int k4 = (fi & 15) << 2;
        float4 v = make_float4(0.f, 0.f, 0.f, 0.f);
        if (row0 + row < n) v = *(const float4*)&src[(size_t)(row0 + row) * 64 + k4];
        At[(k4 + 0) * LDP + row] = v.x;
        At[(k4 + 1) * LDP + row] = v.y;
        At[(k4 + 2) * LDP + row] = v.z;
        At[(k4 + 3) * LDP + row] = v.w;
    }
}

__global__ __launch_bounds__(256) void k_proj(const float* __restrict__ I,
        const float* __restrict__ Wk, const float* __restrict__ Wv,
        const float* __restrict__ UE, const float* __restrict__ Wq,
        bf16* __restrict__ IkB, float* __restrict__ Iv, float* __restrict__ Uq, int IB) {
    __shared__ float At[64 * LDP];
    int t = threadIdx.x;
    int b = blockIdx.x;
    int lane = t & 63;
    int wv = __builtin_amdgcn_readfirstlane(t >> 6);
    if (b < IB) {
        int row0 = b << 6;
        stage_rows1(I, At, row0, N_ITEMS, t);
        __syncthreads();
        const float* Wb = ((wv >> 1) ? Wv : Wk) + (wv & 1) * 32;
        float acc[32];
        #pragma unroll
        for (int c = 0; c < 32; c++) acc[c] = 0.f;
        for (int k = 0; k < 64; k++) {
            float a = At[k * LDP + lane];
            const float* wr = Wb + k * 64;
            #pragma unroll
            for (int c4 = 0; c4 < 8; c4++) {
                float4 w4 = *(const float4*)&wr[c4 * 4];
                acc[c4 * 4 + 0] += a * w4.x;
                acc[c4 * 4 + 1] += a * w4.y;
                acc[c4 * 4 + 2] += a * w4.z;
                acc[c4 * 4 + 3] += a * w4.w;
            }
        }
        int row = row0 + lane;
        if (row < N_ITEMS) {
            if (wv >> 1) {
                float* dst = Iv + (size_t)row * 64 + (wv & 1) * 32;
                #pragma unroll
                for (int c4 = 0; c4 < 8; c4++)
                    *(float4*)&dst[c4 * 4] = make_float4(acc[c4*4], acc[c4*4+1], acc[c4*4+2], acc[c4*4+3]);
            } else {
                bf16* dst = IkB + (size_t)row * 64 + (wv & 1) * 32;
                #pragma unroll
                for (int c4 = 0; c4 < 8; c4++) {
                    ushort4 s;
                    s.x = f2bf_bits(acc[c4 * 4 + 0]);
                    s.y = f2bf_bits(acc[c4 * 4 + 1]);
                    s.z = f2bf_bits(acc[c4 * 4 + 2]);
                    s.w = f2bf_bits(acc[c4 * 4 + 3]);
                    *(ushort4*)&dst[c4 * 4] = s;
                }
            }
        }
    } else {
        int row0 = (b - IB) << 6;
        stage_rows1(UE, At, row0, N_USERS, t);
        __syncthreads();
        const float* Wb = Wq + wv * 16;
        float acc[16];
        #pragma unroll
        for (int c = 0; c < 16; c++) acc[c] = 0.f;
        for (int k = 0; k < 64; k++) {
            float a = At[k * LDP + lane];
            const float* wr = Wb + k * 64;
            #pragma unroll
            for (int c4 = 0; c4 < 4; c4++) {
                float4 w4 = *(const float4*)&wr[c4 * 4];
                acc[c4 * 4 + 0] += a * w4.x;
                acc[c4 * 4 + 1] += a * w4.y;
                acc[c4 * 4 + 2] += a * w4.z;
                acc[c4 * 4 + 3] += a * w4.w;
            }
        }
        int row = row0 + lane;
        if (row < N_USERS) {
            float* dst = Uq + (size_t)row * 64 + wv * 16;
            #pragma unroll
            for (int c4 = 0; c4 < 4; c4++)
                *(float4*)&dst[c4 * 4] = make_float4(acc[c4*4], acc[c4*4+1], acc[c4*4+2], acc[c4*4+3]);
        }
    }
}

// ================= Stage A: fused scores+softmax+scatter =================
__global__ __launch_bounds__(256) void k_userAB(const int* __restrict__ offU,
                        const int2* __restrict__ itw,
                        const float* __restrict__ Uq, const bf16* __restrict__ IkB,
                        float* __restrict__ exA, float* __restrict__ c, int n) {
    int u = (blockIdx.x * blockDim.x + threadIdx.x) >> 6;
    int lane = threadIdx.x & 63;
    if (u >= n) return;
    int s = offU[u], e = offU[u + 1];
    if (s == e) return;
    int l = lane & 15, g = lane >> 4;
    float4 qv = *(const float4*)&Uq[(size_t)u * D + l * 4];
    const char* kbase = (const char*)IkB;
    unsigned dby = (unsigned)(l << 3);
    float den = 0.f;
    for (int j0 = s; j0 < e; j0 += 8) {
        int jA = j0 + g, jB = jA + 4;
        bool vA = jA < e, vB = jB < e;
        int2 iA = itw[vA ? jA : s];
        int2 iB = itw[vB ? jB : s];
        ushort4 kA = *(const ushort4*)(kbase + (((unsigned)iA.x) << 7) + dby);
        ushort4 kB = *(const ushort4*)(kbase + (((unsigned)iB.x) << 7) + dby);
        float dA = qv.x * bits2f(kA.x) + qv.y * bits2f(kA.y) +
                   qv.z * bits2f(kA.z) + qv.w * bits2f(kA.w);
        float dB = qv.x * bits2f(kB.x) + qv.y * bits2f(kB.y) +
                   qv.z * bits2f(kB.z) + qv.w * bits2f(kB.w);
        #pragma unroll
        for (int off = 1; off < 16; off <<= 1) {
            dA += __shfl_xor(dA, off, 64);
            dB += __shfl_xor(dB, off, 64);
        }
        float eAv = vA ? __expf(dA * 0.125f * __int_as_float(iA.y)) : 0.f;
        float eBv = vB ? __expf(dB * 0.125f * __int_as_float(iB.y)) : 0.f;
        den += eAv + eBv;
        if (vA && l == 0) exA[jA] = eAv;
        if (vB && l == 0) exA[jB] = eBv;
    }
    den += __shfl_xor(den, 16, 64);
    den += __shfl_xor(den, 32, 64);
    float inv = __fdividef(1.0f, den * (float)(e - s));   // 1/(den*deg)
    asm volatile("s_waitcnt vmcnt(0)" ::: "memory");
    for (int j = s + lane; j < e; j += 64)
        atomicAdd(&c[itw[j].x], exA[j] * inv);
}

__global__ void k_pdense(const float* __restrict__ c, const float* __restrict__ Iv,
                         float* __restrict__ p, int n) {
    int lane = threadIdx.x & 63;
    int gw = blockIdx.x * 4 + (threadIdx.x >> 6);
    int nw = gridDim.x * 4;
    float acc = 0.f;
    for (int i = gw; i < n; i += nw) acc += c[i] * Iv[(size_t)i * D + lane];
    __shared__ float red[256];
    red[threadIdx.x] = acc;
    __syncthreads();
    if (threadIdx.x < 64) {
        float s = red[threadIdx.x] + red[threadIdx.x + 64] + red[threadIdx.x + 128] + red[threadIdx.x + 192];
        atomicAdd(&p[threadIdx.x], s);
    }
}

// ================= Stage B: fused single-stage, MERGED k-loop =================
// blocks [0,EB): stage once, one k-loop -> EH/ET (acc[32]) AND PHI (acp[16])
// block EB: rel tables; block EB+1: v2/cb
__global__ __launch_bounds__(256) void k_entabx(const float* __restrict__ er,
        const float* __restrict__ ei, const float* __restrict__ fpW1,
        const float* __restrict__ rr, const float* __restrict__ ri,
        const float* __restrict__ rtW1, const float* __restrict__ rtW2,
        const float* __restrict__ rt_b2, const float* __restrict__ p,
        float* __restrict__ EH, float* __restrict__ ET, float* __restrict__ PHI,
        float* __restrict__ RR1, float* __restrict__ PSI,
        float* __restrict__ v2, float* __restrict__ cb, int EB) {
    __shared__ float At[64 * LDP];
    int b = blockIdx.x;
    int t = threadIdx.x;
    if (b < EB) {
        int row0 = b << 6;
        stage_rows2(er, ei, At, row0, N_ENT, t);
        __syncthreads();
        int lane = t & 63;
        int wv = __builtin_amdgcn_readfirstlane(t >> 6);
        int row = row0 + lane;
        const float* Wb1 = fpW1 + ((wv >> 1) ? (128 * 64) : 0) + (wv & 1) * 32;
        const float* Wb2 = rtW1 + wv * 16;
        float acc[32];
        float acp[16];
        #pragma unroll
        for (int c = 0; c < 32; c++) acc[c] = 0.f;
        #pragma unroll
        for (int c = 0; c < 16; c++) acp[c] = 0.f;
        for (int k = 0; k < 64; k++) {
            float a = At[k * LDP + lane];
            const float* wr1 = Wb1 + k * 64;
            const float* wr2 = Wb2 + k * 64;
            #pragma unroll
            for (int c4 = 0; c4 < 8; c4++) {
                float4 w4 = *(const float4*)&wr1[c4 * 4];
                acc[c4 * 4 + 0] += a * w4.x;
                acc[c4 * 4 + 1] += a * w4.y;
                acc[c4 * 4 + 2] += a * w4.z;
                acc[c4 * 4 + 3] += a * w4.w;
            }
            #pragma unroll
            for (int c4 = 0; c4 < 4; c4++) {
                float4 w4 = *(const float4*)&wr2[c4 * 4];
                acp[c4 * 4 + 0] += a * w4.x;
                acp[c4 * 4 + 1] += a * w4.y;
                acp[c4 * 4 + 2] += a * w4.z;
                acp[c4 * 4 + 3] += a * w4.w;
            }
        }
        if (row < N_ENT) {
            float* dst = ((wv >> 1) ? ET : EH) + (size_t)row * 64 + (wv & 1) * 32;
            #pragma unroll
            for (int c4 = 0; c4 < 8; c4++)
                *(float4*)&dst[c4 * 4] = make_float4(acc[c4*4], acc[c4*4+1], acc[c4*4+2], acc[c4*4+3]);
            float* dsp = PHI + (size_t)row * 64 + wv * 16;
            #pragma unroll
            for (int c4 = 0; c4 < 4; c4++)
                *(float4*)&dsp[c4 * 4] = make_float4(acp[c4*4], acp[c4*4+1], acp[c4*4+2], acp[c4*4+3]);
        }
    } else if (b == EB) {
        if (t < 64) {
            int lane = t;
            for (int r = 0; r < 10; r++) {
                float a = 0.f, bb = 0.f;
                for (int k = 0; k < 32; k++) {
                    float sr = rr[r * 32 + k], si = ri[r * 32 + k];
                    a  += sr * fpW1[(64 + k) * D + lane] + si * fpW1[(96 + k) * D + lane];
                    bb += sr * rtW1[k * D + lane] + si * rtW1[(32 + k) * D + lane];
                }
                RR1[r * D + lane] = a;
                PSI[r * D + lane] = bb;
            }
        }
    } else {
        if (t < 64) {
            int j = t;
            float acc = 0.f;
            #pragma unroll
            for (int k = 0; k < D; k++) acc += rtW2[j * D + k] * p[k];
            v2[j] = acc;
            float cc = rt_b2[j] * p[j];
            cc = wave_sum(cc);
            if (j == 0) cb[0] = cc;
        }
    }
}

// ================= omega pass 1: EDGE-PARALLEL gates + omega =================
// 16-lane group per edge; 2 chains (jA, jA+16) per group; NE % 32 == 0 (no tail).
// blocks >= NB: entity_emb -> eA cvt.
__global__ __launch_bounds__(256) void k_omegaE(const int2* __restrict__ csr_th,
                          const float* __restrict__ EH, const float* __restrict__ ET,
                          const float* __restrict__ PHI, const float* __restrict__ PSI,
                          const float* __restrict__ RR1, const float* __restrict__ fp_b1,
                          const float* __restrict__ fpW2, const float* __restrict__ fp_b2,
                          const float* __restrict__ rt_b1, const float* __restrict__ v2,
                          const float* __restrict__ cb, float* __restrict__ omg,
                          const float* __restrict__ src_emb, bf16* __restrict__ eA,
                          int NB) {
    int b = blockIdx.x;
    if (b >= NB) {
        int base = (b - NB) * 1024 + threadIdx.x * 4;
        float4 v = *(const float4*)&src_emb[base];
        ushort4 s;
        s.x = f2bf_bits(v.x); s.y = f2bf_bits(v.y);
        s.z = f2bf_bits(v.z); s.w = f2bf_bits(v.w);
        *(ushort4*)&eA[base] = s;
        return;
    }
    int grp = threadIdx.x >> 4;
    int l = threadIdx.x & 15;
    int d0 = l * 4;
    int jA = b * 32 + grp;
    int jB = jA + 16;
    // per-lane constants
    float4 b1 = *(const float4*)&fp_b1[d0];
    float4 rb = *(const float4*)&rt_b1[d0];
    float4 vv = *(const float4*)&v2[d0];
    float cc = cb[0];
    float f0[4], f1[4], f2[4];
    #pragma unroll
    for (int c4 = 0; c4 < 4; c4++) {
        f0[c4] = fpW2[(d0 + c4) * 3 + 0];
        f1[c4] = fpW2[(d0 + c4) * 3 + 1];
        f2[c4] = fpW2[(d0 + c4) * 3 + 2];
    }
    float b20 = fp_b2[0], b21 = fp_b2[1], b22 = fp_b2[2];
    int2 thA = csr_th[jA];
    int2 thB = csr_th[jB];
    int tA = thA.x & 0xFFFFF, rA = thA.x >> 20, hA = thA.y;
    int tB = thB.x & 0xFFFFF, rB = thB.x >> 20, hB = thB.y;
    float4 ehA = *(const float4*)&EH[(size_t)hA * D + d0];
    float4 ehB = *(const float4*)&EH[(size_t)hB * D + d0];
    float4 phA = *(const float4*)&PHI[(size_t)hA * D + d0];
    float4 phB = *(const float4*)&PHI[(size_t)hB * D + d0];
    float4 etA = *(const float4*)&ET[(size_t)tA * D + d0];
    float4 etB = *(const float4*)&ET[(size_t)tB * D + d0];
    float4 ptA = *(const float4*)&PHI[(size_t)tA * D + d0];
    float4 ptB = *(const float4*)&PHI[(size_t)tB * D + d0];
    float4 rrA = *(const float4*)&RR1[rA * D + d0];
    float4 rrB = *(const float4*)&RR1[rB * D + d0];
    float4 psA = *(const float4*)&PSI[rA * D + d0];
    float4 psB = *(const float4*)&PSI[rB * D + d0];
    ehA.x += b1.x; ehA.y += b1.y; ehA.z += b1.z; ehA.w += b1.w;
    ehB.x += b1.x; ehB.y += b1.y; ehB.z += b1.z; ehB.w += b1.w;
    // gate weights
    float zA0 = sigmoidf(ehA.x + rrA.x + etA.x);
    float zA1 = sigmoidf(ehA.y + rrA.y + etA.y);
    float zA2 = sigmoidf(ehA.z + rrA.z + etA.z);
    float zA3 = sigmoidf(ehA.w + rrA.w + etA.w);
    float zB0 = sigmoidf(ehB.x + rrB.x + etB.x);
    float zB1 = sigmoidf(ehB.y + rrB.y + etB.y);
    float zB2 = sigmoidf(ehB.z + rrB.z + etB.z);
    float zB3 = sigmoidf(ehB.w + rrB.w + etB.w);
    float v[6];
    v[0] = zA0 * f0[0] + zA1 * f0[1] + zA2 * f0[2] + zA3 * f0[3];
    v[1] = zA0 * f1[0] + zA1 * f1[1] + zA2 * f1[2] + zA3 * f1[3];
    v[2] = zA0 * f2[0] + zA1 * f2[1] + zA2 * f2[2] + zA3 * f2[3];
    v[3] = zB0 * f0[0] + zB1 * f0[1] + zB2 * f0[2] + zB3 * f0[3];
    v[4] = zB0 * f1[0] + zB1 * f1[1] + zB2 * f1[2] + zB3 * f1[3];
    v[5] = zB0 * f2[0] + zB1 * f2[1] + zB2 * f2[2] + zB3 * f2[3];
    #pragma unroll
    for (int off = 1; off < 16; off <<= 1) {
        #pragma unroll
        for (int q = 0; q < 6; q++) v[q] += __shfl_xor(v[q], off, 64);
    }
    // softmax (group-uniform)
    float a0 = v[0] + b20, a1 = v[1] + b21, a2 = v[2] + b22;
    float mx = fmaxf(a0, fmaxf(a1, a2));
    float e0 = __expf(a0 - mx), e1 = __expf(a1 - mx), e2 = __expf(a2 - mx);
    float isum = __fdividef(1.0f, e0 + e1 + e2);
    float WA0 = e0 * isum, WA1 = e1 * isum, WA2 = e2 * isum;
    a0 = v[3] + b20; a1 = v[4] + b21; a2 = v[5] + b22;
    mx = fmaxf(a0, fmaxf(a1, a2));
    e0 = __expf(a0 - mx); e1 = __expf(a1 - mx); e2 = __expf(a2 - mx);
    isum = __fdividef(1.0f, e0 + e1 + e2);
    float WB0 = e0 * isum, WB1 = e1 * isum, WB2 = e2 * isum;
    // omega
    float svA = sigmoidf(WA0 * phA.x + WA1 * psA.x + WA2 * ptA.x + rb.x) * vv.x
              + sigmoidf(WA0 * phA.y + WA1 * psA.y + WA2 * ptA.y + rb.y) * vv.y
              + sigmoidf(WA0 * phA.z + WA1 * psA.z + WA2 * ptA.z + rb.z) * vv.z
              + sigmoidf(WA0 * phA.w + WA1 * psA.w + WA2 * ptA.w + rb.w) * vv.w;
    float svB = sigmoidf(WB0 * phB.x + WB1 * psB.x + WB2 * ptB.x + rb.x) * vv.x
              + sigmoidf(WB0 * phB.y + WB1 * psB.y + WB2 * ptB.y + rb.y) * vv.y
              + sigmoidf(WB0 * phB.z + WB1 * psB.z + WB2 * ptB.z + rb.z) * vv.z
              + sigmoidf(WB0 * phB.w + WB1 * psB.w + WB2 * ptB.w + rb.w) * vv.w;
    #pragma unroll
    for (int off = 1; off < 16; off <<= 1) {
        svA += __shfl_xor(svA, off, 64);
        svB += __shfl_xor(svB, off, 64);
    }
    if (l == 0) {
        omg[jA] = (svA + cc) * 0.125f;
        omg[jB] = (svB + cc) * 0.125f;
    }
}

// ================= omega pass 2: per-head segO + alpha + eta =================
// 16-lane group per head.
__global__ __launch_bounds__(256) void k_omegaS(const int* __restrict__ offH,
                          const int2* __restrict__ csr_th,
                          const float* __restrict__ omg,
                          int2* __restrict__ pa, int2* __restrict__ pe, int n) {
    int h = (blockIdx.x * 256 + threadIdx.x) >> 4;
    int l = threadIdx.x & 15;
    if (h >= n) return;
    int s = offH[h], e = offH[h + 1];
    if (s == e) return;
    float so = 0.f;
    for (int j = s + l; j < e; j += 16) so += omg[j];
    so = g16_sum(so);
    float invO = __fdividef(1.0f, so + 1e-8f);
    float se = 0.f;
    for (int j = s + l; j < e; j += 16) {
        float a = omg[j] * invO;
        pa[j] = make_int2(csr_th[j].x, __float_as_int(a));
        se += (a > GAMMA) ? a : 0.0f;
    }
    se = g16_sum(se);
    float invE = __fdividef(1.0f, se + 1e-8f);
    for (int j = s + l; j < e; j += 16) {
        float a = omg[j] * invO;
        pe[j] = make_int2(csr_th[j].x, __float_as_int(((a > GAMMA) ? a : 0.0f) * invE));
    }
}

// ================= fused hop: 16-lane group per node =================
// entity side: 2-edge chains (deg~5); user side: 4-edge chains (deg~20)
__global__ __launch_bounds__(256) void k_hop(const int* __restrict__ offH,
                      const int2* __restrict__ rt,
                      const float* __restrict__ rel,
                      const int* __restrict__ offU, const int2* __restrict__ itw,
                      const bf16* __restrict__ ecur, bf16* __restrict__ enxt,
                      const float* __restrict__ initE, const float* __restrict__ initU,
                      float* __restrict__ outE, float* __restrict__ outU,
                      int init, int EB2) {
    int b = blockIdx.x;
    int l = threadIdx.x & 15;
    int d0 = l * 4;
    const char* ebase = (const char*)ecur;
    unsigned dby = (unsigned)(d0 << 1);
    if (b < EB2) {
        int gw = (b * 256 + threadIdx.x) >> 4;
        if (gw >= N_ENT) return;
        int s = offH[gw], e = offH[gw + 1];
        float a0 = 0.f, a1 = 0.f, a2 = 0.f, a3 = 0.f;
        for (int j0 = s; j0 < e; j0 += 2) {
            int jB = j0 + 1;
            bool vB = jB < e;
            int2 pA = rt[j0];
            int2 pB = rt[vB ? jB : j0];
            float rhA = __int_as_float(pA.y);
            float rhB = vB ? __int_as_float(pB.y) : 0.f;
            unsigned tA = (unsigned)pA.x & 0xFFFFFu; int rA = pA.x >> 20;
            unsigned tB = (unsigned)pB.x & 0xFFFFFu; int rB = pB.x >> 20;
            ushort4 evA = *(const ushort4*)(ebase + (tA << 7) + dby);
            ushort4 evB = *(const ushort4*)(ebase + (tB << 7) + dby);
            float4 rlA = *(const float4*)&rel[rA * D + d0];
            float4 rlB = *(const float4*)&rel[rB * D + d0];
            a0 += rhA * bits2f(evA.x) * rlA.x;
            a1 += rhA * bits2f(evA.y) * rlA.y;
            a2 += rhA * bits2f(evA.z) * rlA.z;
            a3 += rhA * bits2f(evA.w) * rlA.w;
            a0 += rhB * bits2f(evB.x) * rlB.x;
            a1 += rhB * bits2f(evB.y) * rlB.y;
            a2 += rhB * bits2f(evB.z) * rlB.z;
            a3 += rhB * bits2f(evB.w) * rlB.w;
        }
        float invd = __fdividef(1.0f, fmaxf((float)(e - s), 1.0f));
        a0 *= invd; a1 *= invd; a2 *= invd; a3 *= invd;
        float ss = a0 * a0 + a1 * a1 + a2 * a2 + a3 * a3;
        ss = g16_sum(ss);
        float nrm = fmaxf(sqrtf(ss), 1e-8f);
        float innrm = __fdividef(1.0f, nrm);
        float y0 = n2n(a0 * innrm), y1 = n2n(a1 * innrm), y2 = n2n(a2 * innrm), y3 = n2n(a3 * innrm);
        ushort4 st;
        st.x = f2bf_bits(y0); st.y = f2bf_bits(y1); st.z = f2bf_bits(y2); st.w = f2bf_bits(y3);
        *(ushort4*)&enxt[(size_t)gw * D + d0] = st;
        size_t o = (size_t)gw * D + d0;
        float4 prev;
        if (init) prev = *(const float4*)&initE[o];
        else      prev = *(const float4*)&outE[o];
        *(float4*)&outE[o] = make_float4(prev.x + y0, prev.y + y1, prev.z + y2, prev.w + y3);
    } else {
        int gw = ((b - EB2) * 256 + threadIdx.x) >> 4;
        if (gw >= N_USERS) return;
        int s = offU[gw], e = offU[gw + 1];
        float a0 = 0.f, a1 = 0.f, a2 = 0.f, a3 = 0.f;
        for (int j0 = s; j0 < e; j0 += 4) {
            int j1 = j0 + 1, j2 = j0 + 2, j3 = j0 + 3;
            bool v1 = j1 < e, v2c = j2 < e, v3 = j3 < e;
            int2 i0 = itw[j0];
            int2 i1 = itw[v1 ? j1 : j0];
            int2 i2 = itw[v2c ? j2 : j0];
            int2 i3 = itw[v3 ? j3 : j0];
            float w0 = __int_as_float(i0.y);
            float w1 = v1 ? __int_as_float(i1.y) : 0.f;
            float w2 = v2c ? __int_as_float(i2.y) : 0.f;
            float w3 = v3 ? __int_as_float(i3.y) : 0.f;
            ushort4 e0 = *(const ushort4*)(ebase + (((unsigned)i0.x) << 7) + dby);
            ushort4 e1 = *(const ushort4*)(ebase + (((unsigned)i1.x) << 7) + dby);
            ushort4 e2 = *(const ushort4*)(ebase + (((unsigned)i2.x) << 7) + dby);
            ushort4 e3 = *(const ushort4*)(ebase + (((unsigned)i3.x) << 7) + dby);
            a0 += w0 * bits2f(e0.x) + w1 * bits2f(e1.x) + w2 * bits2f(e2.x) + w3 * bits2f(e3.x);
            a1 += w0 * bits2f(e0.y) + w1 * bits2f(e1.y) + w2 * bits2f(e2.y) + w3 * bits2f(e3.y);
            a2 += w0 * bits2f(e0.z) + w1 * bits2f(e1.z) + w2 * bits2f(e2.z) + w3 * bits2f(e3.z);
            a3 += w0 * bits2f(e0.w) + w1 * bits2f(e1.w) + w2 * bits2f(e2.w) + w3 * bits2f(e3.w);
        }
        float ss = a0 * a0 + a1 * a1 + a2 * a2 + a3 * a3;
        ss = g16_sum(ss);
        float nrm = fmaxf(sqrtf(ss), 1e-8f);
        float innrm = __fdividef(1.0f, nrm);
        float y0 = n2n(a0 * innrm), y1 = n2n(a1 * innrm), y2 = n2n(a2 * innrm), y3 = n2n(a3 * innrm);
        size_t o = (size_t)gw * D + d0;
        float4 prev;
        if (init) prev = *(const float4*)&initU[o];
        else      prev = *(const float4*)&outU[o];
        *(float4*)&outU[o] = make_float4(prev.x + y0, prev.y + y1, prev.z + y2, prev.w + y3);
    }
}

extern "C" void kernel_launch(void* const* d_in, const int* in_sizes, int n_in,
                              void* d_out, int out_size, void* d_ws, size_t ws_size,
                              hipStream_t stream) {
    const float* user_embed = (const float*)d_in[0];
    const float* item_embed = (const float*)d_in[1];
    const float* Wq = (const float*)d_in[2];
    const float* Wk = (const float*)d_in[3];
    const float* Wv = (const float*)d_in[4];
    const float* ent_real = (const float*)d_in[5];
    const float* ent_imag = (const float*)d_in[6];
    const float* rel_real = (const float*)d_in[7];
    const float* rel_imag = (const float*)d_in[8];
    const float* fp_W1 = (const float*)d_in[9];
    const float* fp_b1 = (const float*)d_in[10];
    const float* fp_W2 = (const float*)d_in[11];
    const float* fp_b2 = (const float*)d_in[12];
    const float* rt_W1 = (const float*)d_in[13];
    const float* rt_b1 = (const float*)d_in[14];
    const float* rt_W2 = (const float*)d_in[15];
    const float* rt_b2 = (const float*)d_in[16];
    const float* relation_emb = (const float*)d_in[17];
    const float* user_emb = (const float*)d_in[18];
    const float* entity_emb = (const float*)d_in[19];
    const float* inter_edge_w = (const float*)d_in[20];
    const int* edge_index = (const int*)d_in[21];
    const int* edge_type = (const int*)d_in[22];
    const int* inter_edge = (const int*)d_in[23];
    float* out = (float*)d_out;

    float* W = (float*)d_ws;
    size_t off = 0;
    auto alloc = [&](size_t n) { float* r = W + off; off += n; return r; };
    // persistent floats
    float* omg    = alloc(NE);
    float* exA    = alloc(NEI);
    float* c      = alloc(N_ITEMS);   // c and p adjacent -> single memset
    float* p      = alloc(64);
    float* v2     = alloc(64);
    float* cb     = alloc(64);
    float* RR1    = alloc(10 * D);
    float* PSI    = alloc(10 * D);
    // persistent ints
    off = (off + 3) & ~(size_t)3;
    int* IW = (int*)(W + off);
    size_t ioff = 0;
    auto ialloc = [&](size_t n) { int* r = IW + ioff; ioff += n; return r; };
    int2* csr_itw = (int2*)ialloc(2 * (size_t)NEI);   // packed (item, wbits)
    int2* pa      = (int2*)ialloc(2 * (size_t)NE);    // packed (tr, alpha)
    int2* pe      = (int2*)ialloc(2 * (size_t)NE);    // packed (tr, eta)
    int2* csr_th  = (int2*)ialloc(2 * (size_t)NE);    // packed (tr, head)
    int* offU   = ialloc(N_USERS + 1);
    int* offH   = ialloc(N_ENT + 1);
    int* bcntU  = ialloc(UBK);                // bcntU/bcntH adjacent -> single memset
    int* bcntH  = ialloc(HBK);
    int* bOffU  = ialloc(UBK + 1);
    int* bOffH  = ialloc(HBK + 1);
    int* bcurU  = ialloc(UBK);
    int* bcurH  = ialloc(HBK);
    off += ioff;
    off = (off + 3) & ~(size_t)3;
    // union region
    float* U = W + off;
    const size_t NED = (size_t)N_ENT * D;       // 6.4M floats
    // CSR-build staging (dead before k_proj launches)
    int2* stIW = (int2*)U;                      // NEI packed (item|ul<<24, wbits)
    int*  stTR = (int*)U + 2 * (size_t)NEI;     // NE packed (t | r<<20 | hl<<24)
    // phase B tables (written by k_entabx, read by k_omegaE)
    float* EH  = U;
    float* ET  = U + NED;
    float* PHI = U + 2 * NED;
    // phase A outputs live ABOVE the tables
    float* XR  = U + 3 * NED;
    bf16*  IkB = (bf16*)XR;
    float* Iv  = XR + (size_t)N_ITEMS * 32;
    float* Uq  = Iv + (size_t)N_ITEMS * D;
    // eA overlaps IkB/Iv/Uq (dead by omegaE); eB over dead EH region (hops)
    bf16* eA = (bf16*)XR;
    bf16* eB = (bf16*)U;

    const int UCH = (NEI + PCHUNK - 1) / PCHUNK;   // 245
    const int HCH = (NE + PCHUNK - 1) / PCHUNK;    // 123
    const int IB = (N_ITEMS + 63) / 64;            // 469
    const int UB = (N_USERS + 63) / 64;            // 782
    const int EB = (N_ENT + 63) / 64;              // 1563
    const int OEB = NE / 32;                       // 15625 edge blocks (exact)
    const int CB = (N_ENT * D) / 1024;             // cvt blocks (exact)
    const int SB = (N_ENT + 15) / 16;
    const int HE2 = (N_ENT + 15) / 16;
    const int HU2 = (N_USERS + 15) / 16;

    // ---- CSR build (bucketed 2-pass multisplit) ----
    hipMemsetAsync(bcntU, 0, (UBK + HBK) * 4, stream);
    hipMemsetAsync(c, 0, (N_ITEMS + 64) * 4, stream);
    k_histb<<<UCH + HCH, 256, 0, stream>>>(inter_edge, edge_index, bcntU, bcntH, UCH);
    k_scanb<<<2, 512, 0, stream>>>(bcntU, bOffU, bcurU, bcntH, bOffH, bcurH, offU, offH);
    k_part1<<<UCH + HCH, 256, 0, stream>>>(inter_edge, inter_edge_w, edge_index,
                                           edge_type, bcurU, bcurH, stIW, stTR, UCH);
    k_part2<<<UBK + HBK, 256, 0, stream>>>(bOffU, stIW, offU, csr_itw,
                                           bOffH, stTR, offH, csr_th, UBK);

    // ---- Phase A ----
    k_proj<<<IB + UB, 256, 0, stream>>>(item_embed, Wk, Wv, user_embed, Wq,
                                        IkB, Iv, Uq, IB);
    k_userAB<<<(N_USERS + 3) / 4, 256, 0, stream>>>(offU, csr_itw, Uq, IkB, exA, c, N_USERS);
    k_pdense<<<64, 256, 0, stream>>>(c, Iv, p, N_ITEMS);

    // ---- Phase B ----
    k_entabx<<<EB + 2, 256, 0, stream>>>(ent_real, ent_imag, fp_W1, rel_real, rel_imag,
                                         rt_W1, rt_W2, rt_b2, p, EH, ET, PHI,
                                         RR1, PSI, v2, cb, EB);
    k_omegaE<<<OEB + CB, 256, 0, stream>>>(csr_th, EH, ET, PHI, PSI, RR1,
                                           fp_b1, fp_W2, fp_b2, rt_b1, v2, cb,
                                           omg, entity_emb, eA, OEB);
    k_omegaS<<<SB, 256, 0, stream>>>(offH, csr_th, omg, pa, pe, N_ENT);

    // ---- hops ----
    bf16* ecur = eA;
    bf16* enxt = eB;
    for (int hop = 1; hop <= 3; hop++) {
        const int2* rt = (hop < 3) ? pa : pe;
        int init = (hop == 1) ? 1 : 0;
        k_hop<<<HE2 + HU2, 256, 0, stream>>>(offH, rt, relation_emb,
                                             offU, csr_itw, ecur, enxt,
                                             entity_emb, user_emb,
                                             out, out + (size_t)N_ENT * D, init, HE2);
        bf16* tmp = ecur; ecur = enxt; enxt = tmp;
    }
}